// Round 1
// 1797.744 us; speedup vs baseline: 6.1251x; 6.1251x over previous
//
#include <hip/hip_runtime.h>
#include <hip/hip_bf16.h>
#include <math.h>

typedef __bf16 bf16;
typedef __bf16 bf16x8 __attribute__((ext_vector_type(8)));
typedef float f32x4 __attribute__((ext_vector_type(4)));

#define GL_AS(p) ((const __attribute__((address_space(1))) void*)(p))
#define LDS_AS(p) ((__attribute__((address_space(3))) void*)(p))

// ---------------------------------------------------------------------------
// Transpose + f32->bf16 cast:  in [R,C] f32 (batched on z)  ->  out [C,R] bf16
// ---------------------------------------------------------------------------
__global__ __launch_bounds__(256) void transpose_cast_k(
    const float* __restrict__ in, bf16* __restrict__ out, int R, int C)
{
    __shared__ float t[32][33];
    const int c0 = blockIdx.x * 32, r0 = blockIdx.y * 32;
    const size_t zoff = (size_t)blockIdx.z * R * C;
    const float* inb = in + zoff;
    bf16* outb = out + zoff;
    const int tx = threadIdx.x, ty = threadIdx.y;   // (32, 8)
#pragma unroll
    for (int i = 0; i < 32; i += 8)
        t[ty + i][tx] = inb[(size_t)(r0 + ty + i) * C + c0 + tx];
    __syncthreads();
#pragma unroll
    for (int i = 0; i < 32; i += 8)
        outb[(size_t)(c0 + ty + i) * R + r0 + tx] = (bf16)t[tx][ty + i];
}

// ---------------------------------------------------------------------------
// V transpose: qkv [B*S, 3072] bf16 (v at col 2048 + hd) -> vt [B][1024 hd][1024 s]
// ---------------------------------------------------------------------------
__global__ __launch_bounds__(256) void vtrans_k(
    const bf16* __restrict__ qkv, bf16* __restrict__ vt)
{
    __shared__ float t[32][33];
    const int c0 = blockIdx.x * 32, r0 = blockIdx.y * 32;   // r = s, c = hd
    const int b = blockIdx.z;
    const int tx = threadIdx.x, ty = threadIdx.y;           // (32, 8)
#pragma unroll
    for (int i = 0; i < 32; i += 8)
        t[ty + i][tx] = (float)qkv[(size_t)(b * 1024 + r0 + ty + i) * 3072 + 2048 + c0 + tx];
    __syncthreads();
#pragma unroll
    for (int i = 0; i < 32; i += 8)
        vt[(size_t)(b * 1024 + c0 + ty + i) * 1024 + r0 + tx] = (bf16)t[tx][ty + i];
}

// ---------------------------------------------------------------------------
// Embedding + sinusoidal positional encoding -> x f32 [B*S, 1024]
// ---------------------------------------------------------------------------
__global__ __launch_bounds__(256) void embed_k(
    const int* __restrict__ tok, const float* __restrict__ emb,
    float* __restrict__ x)
{
    const int D = 1024;
    const int row = blockIdx.x;
    const int s = row & 1023;          // S = 1024
    const int t = tok[row];
#pragma unroll
    for (int i = 0; i < 4; ++i) {
        const int d = threadIdx.x + i * 256;
        const int half = d >> 1;
        const float div = expf(-(float)half * (9.210340371976184f / 512.0f));
        const float ang = (float)s * div;
        const float pe = (d & 1) ? cosf(ang) : sinf(ang);
        x[(size_t)row * D + d] = emb[(size_t)t * D + d] + pe;
    }
}

// ---------------------------------------------------------------------------
// LayerNorm (D=1024): x f32 -> out bf16
// ---------------------------------------------------------------------------
__global__ __launch_bounds__(256) void layernorm_k(
    const float* __restrict__ x, const float* __restrict__ sc,
    const float* __restrict__ bi, bf16* __restrict__ out)
{
    const int D = 1024;
    const int row = blockIdx.x;
    const float* xr = x + (size_t)row * D;
    float vals[4];
    float s = 0.f, q = 0.f;
#pragma unroll
    for (int i = 0; i < 4; ++i) {
        const float v = xr[threadIdx.x + i * 256];
        vals[i] = v; s += v; q += v * v;
    }
#pragma unroll
    for (int o = 32; o; o >>= 1) { s += __shfl_xor(s, o); q += __shfl_xor(q, o); }
    __shared__ float ls[4], lq[4];
    const int w = threadIdx.x >> 6;
    if ((threadIdx.x & 63) == 0) { ls[w] = s; lq[w] = q; }
    __syncthreads();
    const float S = ls[0] + ls[1] + ls[2] + ls[3];
    const float Q = lq[0] + lq[1] + lq[2] + lq[3];
    const float mu = S * (1.0f / D);
    const float var = Q * (1.0f / D) - mu * mu;
    const float rstd = rsqrtf(var + 1e-5f);
#pragma unroll
    for (int i = 0; i < 4; ++i) {
        const int d = threadIdx.x + i * 256;
        out[(size_t)row * D + d] = (bf16)((vals[i] - mu) * rstd * sc[d] + bi[d]);
    }
}

// ---------------------------------------------------------------------------
// GEMM: C[M,N] = A[M,K](bf16) @ Bt[N,K](bf16)^T, f32 accum, various epilogues
// 128x128 tile, BK=64, 4 waves (2x2), mfma_f32_16x16x32_bf16
// EPI: 0 store bf16 | 1 Cf += acc | 2 bias+gelu->bf16 | 3 Cf += acc+bias | 4 Cf = acc+bias
// ---------------------------------------------------------------------------
template <int EPI>
__global__ __launch_bounds__(256, 2) void gemm_bt_k(
    const bf16* __restrict__ A, const bf16* __restrict__ Bt,
    float* __restrict__ Cf, bf16* __restrict__ Cb,
    const float* __restrict__ bias, int M, int N, int K)
{
    __shared__ __align__(16) bf16 Al[128 * 64];
    __shared__ __align__(16) bf16 Bl[128 * 64];
    const int tid = threadIdx.x;
    const int l = tid & 63;
    const int wbase = tid & 192;                 // wave_id * 64
    const int wr = (tid >> 7) & 1, wc = (tid >> 6) & 1;
    const int bm = blockIdx.x, bn = blockIdx.y;

    f32x4 acc[4][4];
#pragma unroll
    for (int i = 0; i < 4; ++i)
#pragma unroll
        for (int j = 0; j < 4; ++j) acc[i][j] = (f32x4){0.f, 0.f, 0.f, 0.f};

    const bf16* Abase = A + (size_t)bm * 128 * K;
    const bf16* Bbase = Bt + (size_t)bn * 128 * K;

    for (int k0 = 0; k0 < K; k0 += 64) {
        // ---- stage A and B tiles: [128 rows][64 k] bf16, XOR-swizzled slots.
        // chunk c (16B): row=c>>3 slot=c&7; global col-block = slot ^ (row&7)
#pragma unroll
        for (int i = 0; i < 4; ++i) {
            const int c = i * 256 + tid;
            const int row = c >> 3, slot = c & 7;
            const int col = ((slot ^ (row & 7)) << 3);
            __builtin_amdgcn_global_load_lds(
                GL_AS(Abase + (size_t)row * K + k0 + col),
                LDS_AS(Al + (i * 256 + wbase) * 8), 16, 0, 0);
        }
#pragma unroll
        for (int i = 0; i < 4; ++i) {
            const int c = i * 256 + tid;
            const int row = c >> 3, slot = c & 7;
            const int col = ((slot ^ (row & 7)) << 3);
            __builtin_amdgcn_global_load_lds(
                GL_AS(Bbase + (size_t)row * K + k0 + col),
                LDS_AS(Bl + (i * 256 + wbase) * 8), 16, 0, 0);
        }
        __syncthreads();   // drains vmcnt: tiles visible

#pragma unroll
        for (int ks = 0; ks < 2; ++ks) {
            bf16x8 af[4], bfr[4];
            const int kb = ks * 64 + ((l >> 4) << 4);   // byte offset of lane's k-block
#pragma unroll
            for (int mi = 0; mi < 4; ++mi) {
                const int r = wr * 64 + mi * 16 + (l & 15);
                af[mi] = *(const bf16x8*)((const char*)Al + r * 128 + (kb ^ ((r & 7) << 4)));
            }
#pragma unroll
            for (int ni = 0; ni < 4; ++ni) {
                const int r = wc * 64 + ni * 16 + (l & 15);
                bfr[ni] = *(const bf16x8*)((const char*)Bl + r * 128 + (kb ^ ((r & 7) << 4)));
            }
#pragma unroll
            for (int mi = 0; mi < 4; ++mi)
#pragma unroll
                for (int ni = 0; ni < 4; ++ni)
                    acc[mi][ni] = __builtin_amdgcn_mfma_f32_16x16x32_bf16(
                        af[mi], bfr[ni], acc[mi][ni], 0, 0, 0);
        }
        __syncthreads();   // all reads done before next stage overwrites
    }

    // ---- epilogue: C/D layout col=lane&15, row=(lane>>4)*4+j  [m89/m91]
    const int colb = bn * 128 + wc * 64;
    const int rowb = bm * 128 + wr * 64 + ((l >> 4) << 2);
#pragma unroll
    for (int mi = 0; mi < 4; ++mi) {
#pragma unroll
        for (int ni = 0; ni < 4; ++ni) {
            const int col = colb + ni * 16 + (l & 15);
#pragma unroll
            for (int j = 0; j < 4; ++j) {
                const int row = rowb + mi * 16 + j;
                const float v = acc[mi][ni][j];
                if constexpr (EPI == 0) {
                    Cb[(size_t)row * N + col] = (bf16)v;
                } else if constexpr (EPI == 1) {
                    Cf[(size_t)row * N + col] += v;
                } else if constexpr (EPI == 2) {
                    const float u = v + bias[col];
                    const float g = 0.5f * u * (1.0f + erff(u * 0.70710678118654752f));
                    Cb[(size_t)row * N + col] = (bf16)g;
                } else if constexpr (EPI == 3) {
                    Cf[(size_t)row * N + col] += v + bias[col];
                } else {
                    Cf[(size_t)row * N + col] = v + bias[col];
                }
            }
        }
    }
}

// ---------------------------------------------------------------------------
// MFMA flash attention. One wave per block, 16 q-rows per wave.
// grid.x = B*H*(S/16) = 2048.  qkv bf16 [B*S, 3072]: q at h*64+d, k at 1024+h*64+d.
// vt bf16 [B][1024 hd][1024 s] (pre-transposed V).  out o bf16 [B*S, 1024].
//
// Fragment conventions (proven by gemm_bt_k, m89/m91):
//   A-frag: lane l holds A[l&15][(l>>4)*8 + jj]   (8 contiguous k)
//   B-frag: lane l holds B[(l>>4)*8 + jj][l&15]
//   C:      lane l holds C[(l>>4)*4 + j][l&15]
// ---------------------------------------------------------------------------
__global__ __launch_bounds__(64) void attn_mfma_k(
    const bf16* __restrict__ qkv, const bf16* __restrict__ vt,
    bf16* __restrict__ o)
{
    // P round-trip buffer: hi at cols [0..31], lo at cols [48..79]; stride 88
    // (176 B: 16B-aligned rows, not ≡0 mod 128B -> write conflicts ~2-way)
    __shared__ __align__(16) bf16 Pl[16][88];

    const int l = threadIdx.x;          // 0..63
    const int g = l >> 4, lc = l & 15;
    const int qt = blockIdx.x & 63;     // S/16 = 64 q-tiles
    const int bh = blockIdx.x >> 6;
    const int h = bh & 15, b = bh >> 4;
    const int q0 = qt * 16;

    const bf16* qbase = qkv + (size_t)b * 1024 * 3072 + h * 64;
    const bf16* kbase = qbase + 1024;
    const bf16* vbase = vt + (size_t)(b * 16 + h) * 64 * 1024;

    // Q A-frags: lane holds Q[q0+lc][c*32 + g*8 + jj]
    bf16x8 af0, af1;
    {
        const bf16* qp = qbase + (size_t)(q0 + lc) * 3072 + g * 8;
        af0 = *(const bf16x8*)qp;
        af1 = *(const bf16x8*)(qp + 32);
    }

    f32x4 acc[4];                        // O: rows q0+4g+j, cols dt*16+lc
#pragma unroll
    for (int dt = 0; dt < 4; ++dt) acc[dt] = (f32x4){0.f, 0.f, 0.f, 0.f};
    f32x4 m  = (f32x4){-1e30f, -1e30f, -1e30f, -1e30f};
    f32x4 ls = (f32x4){0.f, 0.f, 0.f, 0.f};   // lane-partial row sums

    auto tile = [&](int k0, bool MASKED) {
        // K B-frags: lane holds K[k0+16t+lc][c*32 + g*8 + jj]
        const int kr0 = k0 + lc;
        const int kr1 = MASKED ? min(k0 + 16 + lc, 1023) : (k0 + 16 + lc);
        const bf16* kp0 = kbase + (size_t)kr0 * 3072 + g * 8;
        const bf16* kp1 = kbase + (size_t)kr1 * 3072 + g * 8;
        const bf16x8 kf00 = *(const bf16x8*)kp0;
        const bf16x8 kf01 = *(const bf16x8*)(kp0 + 32);
        const bf16x8 kf10 = *(const bf16x8*)kp1;
        const bf16x8 kf11 = *(const bf16x8*)(kp1 + 32);

        f32x4 s0 = (f32x4){0.f, 0.f, 0.f, 0.f};
        f32x4 s1 = (f32x4){0.f, 0.f, 0.f, 0.f};
        s0 = __builtin_amdgcn_mfma_f32_16x16x32_bf16(af0, kf00, s0, 0, 0, 0);
        s0 = __builtin_amdgcn_mfma_f32_16x16x32_bf16(af1, kf01, s0, 0, 0, 0);
        s1 = __builtin_amdgcn_mfma_f32_16x16x32_bf16(af0, kf10, s1, 0, 0, 0);
        s1 = __builtin_amdgcn_mfma_f32_16x16x32_bf16(af1, kf11, s1, 0, 0, 0);

        // scale (+ causal mask on the diagonal tile)
#pragma unroll
        for (int j = 0; j < 4; ++j) {
            if (MASKED) {
                const int row = q0 + 4 * g + j;
                s0[j] = (kr0 <= row)          ? s0[j] * 0.125f : -1e30f;
                s1[j] = (k0 + 16 + lc <= row) ? s1[j] * 0.125f : -1e30f;
            } else {
                s0[j] *= 0.125f;
                s1[j] *= 0.125f;
            }
        }

        // row-max across the 16 lanes of this group (cols) + both key-halves
        f32x4 t;
#pragma unroll
        for (int j = 0; j < 4; ++j) t[j] = fmaxf(s0[j], s1[j]);
#pragma unroll
        for (int off = 8; off; off >>= 1)
#pragma unroll
            for (int j = 0; j < 4; ++j) t[j] = fmaxf(t[j], __shfl_xor(t[j], off));

        f32x4 sc, p0, p1;
#pragma unroll
        for (int j = 0; j < 4; ++j) {
            const float mn = fmaxf(m[j], t[j]);
            sc[j] = __expf(m[j] - mn);
            p0[j] = __expf(s0[j] - mn);
            p1[j] = __expf(s1[j] - mn);
            m[j] = mn;
            ls[j] = ls[j] * sc[j] + p0[j] + p1[j];
        }
#pragma unroll
        for (int dt = 0; dt < 4; ++dt)
#pragma unroll
            for (int j = 0; j < 4; ++j) acc[dt][j] *= sc[j];

        // P -> LDS in C-layout; read back in A-frag layout. hi/lo bf16 split
        // keeps P at ~24-bit accuracy (numerics match the old f32 attention).
#pragma unroll
        for (int j = 0; j < 4; ++j) {
            const int r = 4 * g + j;
            const bf16 h0 = (bf16)p0[j];
            const bf16 h1 = (bf16)p1[j];
            Pl[r][lc]      = h0;
            Pl[r][16 + lc] = h1;
            Pl[r][48 + lc] = (bf16)(p0[j] - (float)h0);
            Pl[r][64 + lc] = (bf16)(p1[j] - (float)h1);
        }
        const bf16x8 pah = *(const bf16x8*)&Pl[lc][g * 8];
        const bf16x8 pal = *(const bf16x8*)&Pl[lc][48 + g * 8];

        // PV: B-frag of V from pre-transposed vt (contiguous 16B per lane)
        const int sb = MASKED ? min(k0 + g * 8, 1016) : (k0 + g * 8);
#pragma unroll
        for (int dt = 0; dt < 4; ++dt) {
            const bf16x8 vf = *(const bf16x8*)(vbase + (size_t)(dt * 16 + lc) * 1024 + sb);
            acc[dt] = __builtin_amdgcn_mfma_f32_16x16x32_bf16(pah, vf, acc[dt], 0, 0, 0);
            acc[dt] = __builtin_amdgcn_mfma_f32_16x16x32_bf16(pal, vf, acc[dt], 0, 0, 0);
        }
    };

    int k0 = 0;
    for (; k0 + 31 <= q0; k0 += 32) tile(k0, false);
    tile(k0, true);   // exactly one diagonal (masked) tile remains

    // reduce lane-partial row sums across the 16 cols, normalize, store
    f32x4 inv;
#pragma unroll
    for (int j = 0; j < 4; ++j) {
        float s = ls[j];
#pragma unroll
        for (int off = 8; off; off >>= 1) s += __shfl_xor(s, off);
        inv[j] = 1.0f / s;
    }
    bf16* op = o + (size_t)(b * 1024 + q0) * 1024 + h * 64;
#pragma unroll
    for (int dt = 0; dt < 4; ++dt)
#pragma unroll
        for (int j = 0; j < 4; ++j)
            op[(size_t)(4 * g + j) * 1024 + dt * 16 + lc] = (bf16)(acc[dt][j] * inv[j]);
}

// ---------------------------------------------------------------------------
extern "C" void kernel_launch(void* const* d_in, const int* in_sizes, int n_in,
                              void* d_out, int out_size, void* d_ws, size_t ws_size,
                              hipStream_t stream)
{
    const int B = 2, S = 1024, D = 1024, L = 6, F = 4096, V = 32000, H = 16;
    const int M = B * S;

    const int*   tokens    = (const int*)  d_in[0];
    const float* token_emb = (const float*)d_in[1];
    const float* Wqkv      = (const float*)d_in[2];
    const float* Wout      = (const float*)d_in[3];
    const float* ln1_s     = (const float*)d_in[4];
    const float* ln1_b     = (const float*)d_in[5];
    const float* W1        = (const float*)d_in[6];
    const float* b1        = (const float*)d_in[7];
    const float* W2        = (const float*)d_in[8];
    const float* b2        = (const float*)d_in[9];
    const float* ln2_s     = (const float*)d_in[10];
    const float* ln2_b     = (const float*)d_in[11];
    const float* lnf_s     = (const float*)d_in[12];
    const float* lnf_b     = (const float*)d_in[13];
    const float* Whead     = (const float*)d_in[14];
    const float* bhead     = (const float*)d_in[15];
    float* out = (float*)d_out;

    char* w = (char*)d_ws;
    size_t off = 0;
    auto alloc = [&](size_t n) { char* p = w + off; off += (n + 255) & ~(size_t)255; return p; };
    bf16* WqkvT  = (bf16*)alloc((size_t)L * 3 * D * D * 2);
    bf16* WoutT  = (bf16*)alloc((size_t)L * D * D * 2);
    bf16* W1T    = (bf16*)alloc((size_t)L * F * D * 2);
    bf16* W2T    = (bf16*)alloc((size_t)L * D * F * 2);
    bf16* WheadT = (bf16*)alloc((size_t)V * D * 2);
    float* x     = (float*)alloc((size_t)M * D * 4);
    bf16* h      = (bf16*)alloc((size_t)M * D * 2);
    bf16* qkv    = (bf16*)alloc((size_t)M * 3 * D * 2);
    bf16* ob     = (bf16*)alloc((size_t)M * D * 2);
    bf16* mid    = (bf16*)alloc((size_t)M * F * 2);
    // vt aliases mid: vt is live only qkv-GEMM -> attn; mid only W1 -> W2.
    bf16* vt     = mid;   // [B][1024 hd][1024 s] = 4 MB <= 16.8 MB

    const dim3 tb(32, 8);
    transpose_cast_k<<<dim3(3 * D / 32, D / 32, L), tb, 0, stream>>>(Wqkv, WqkvT, D, 3 * D);
    transpose_cast_k<<<dim3(D / 32, D / 32, L),     tb, 0, stream>>>(Wout, WoutT, D, D);
    transpose_cast_k<<<dim3(F / 32, D / 32, L),     tb, 0, stream>>>(W1, W1T, D, F);
    transpose_cast_k<<<dim3(D / 32, F / 32, L),     tb, 0, stream>>>(W2, W2T, F, D);
    transpose_cast_k<<<dim3(V / 32, D / 32, 1),     tb, 0, stream>>>(Whead, WheadT, D, V);

    embed_k<<<M, 256, 0, stream>>>(tokens, token_emb, x);

    for (int lyr = 0; lyr < L; ++lyr) {
        layernorm_k<<<M, 256, 0, stream>>>(x, ln1_s + lyr * D, ln1_b + lyr * D, h);
        gemm_bt_k<0><<<dim3(M / 128, 3 * D / 128), 256, 0, stream>>>(
            h, WqkvT + (size_t)lyr * 3 * D * D, nullptr, qkv, nullptr, M, 3 * D, D);
        vtrans_k<<<dim3(D / 32, S / 32, B), tb, 0, stream>>>(qkv, vt);
        attn_mfma_k<<<B * H * S / 16, 64, 0, stream>>>(qkv, vt, ob);
        gemm_bt_k<1><<<dim3(M / 128, D / 128), 256, 0, stream>>>(
            ob, WoutT + (size_t)lyr * D * D, x, nullptr, nullptr, M, D, D);
        layernorm_k<<<M, 256, 0, stream>>>(x, ln2_s + lyr * D, ln2_b + lyr * D, h);
        gemm_bt_k<2><<<dim3(M / 128, F / 128), 256, 0, stream>>>(
            h, W1T + (size_t)lyr * F * D, nullptr, mid, b1 + lyr * F, M, F, D);
        gemm_bt_k<3><<<dim3(M / 128, D / 128), 256, 0, stream>>>(
            mid, W2T + (size_t)lyr * D * F, x, nullptr, b2 + lyr * D, M, D, F);
    }
    layernorm_k<<<M, 256, 0, stream>>>(x, lnf_s, lnf_b, h);
    gemm_bt_k<4><<<dim3(M / 128, V / 128), 256, 0, stream>>>(
        h, WheadT, out, nullptr, bhead, M, V, D);
}

// Round 2
// 1744.234 us; speedup vs baseline: 6.3130x; 1.0307x over previous
//
#include <hip/hip_runtime.h>
#include <hip/hip_bf16.h>
#include <math.h>

typedef __bf16 bf16;
typedef __bf16 bf16x8 __attribute__((ext_vector_type(8)));
typedef float f32x4 __attribute__((ext_vector_type(4)));

#define GL_AS(p) ((const __attribute__((address_space(1))) void*)(p))
#define LDS_AS(p) ((__attribute__((address_space(3))) void*)(p))

// ---------------------------------------------------------------------------
// Transpose + f32->bf16 cast:  in [R,C] f32 (batched on z)  ->  out [C,R] bf16
// ---------------------------------------------------------------------------
__global__ __launch_bounds__(256) void transpose_cast_k(
    const float* __restrict__ in, bf16* __restrict__ out, int R, int C)
{
    __shared__ float t[32][33];
    const int c0 = blockIdx.x * 32, r0 = blockIdx.y * 32;
    const size_t zoff = (size_t)blockIdx.z * R * C;
    const float* inb = in + zoff;
    bf16* outb = out + zoff;
    const int tx = threadIdx.x, ty = threadIdx.y;   // (32, 8)
#pragma unroll
    for (int i = 0; i < 32; i += 8)
        t[ty + i][tx] = inb[(size_t)(r0 + ty + i) * C + c0 + tx];
    __syncthreads();
#pragma unroll
    for (int i = 0; i < 32; i += 8)
        outb[(size_t)(c0 + ty + i) * R + r0 + tx] = (bf16)t[tx][ty + i];
}

// ---------------------------------------------------------------------------
// V transpose: qkv [B*S, 3072] bf16 (v at col 2048 + hd) -> vt [B][1024 hd][1024 s]
// ---------------------------------------------------------------------------
__global__ __launch_bounds__(256) void vtrans_k(
    const bf16* __restrict__ qkv, bf16* __restrict__ vt)
{
    __shared__ float t[32][33];
    const int c0 = blockIdx.x * 32, r0 = blockIdx.y * 32;   // r = s, c = hd
    const int b = blockIdx.z;
    const int tx = threadIdx.x, ty = threadIdx.y;           // (32, 8)
#pragma unroll
    for (int i = 0; i < 32; i += 8)
        t[ty + i][tx] = (float)qkv[(size_t)(b * 1024 + r0 + ty + i) * 3072 + 2048 + c0 + tx];
    __syncthreads();
#pragma unroll
    for (int i = 0; i < 32; i += 8)
        vt[(size_t)(b * 1024 + c0 + ty + i) * 1024 + r0 + tx] = (bf16)t[tx][ty + i];
}

// ---------------------------------------------------------------------------
// Embedding + sinusoidal positional encoding -> x f32 [B*S, 1024]
// ---------------------------------------------------------------------------
__global__ __launch_bounds__(256) void embed_k(
    const int* __restrict__ tok, const float* __restrict__ emb,
    float* __restrict__ x)
{
    const int D = 1024;
    const int row = blockIdx.x;
    const int s = row & 1023;          // S = 1024
    const int t = tok[row];
#pragma unroll
    for (int i = 0; i < 4; ++i) {
        const int d = threadIdx.x + i * 256;
        const int half = d >> 1;
        const float div = expf(-(float)half * (9.210340371976184f / 512.0f));
        const float ang = (float)s * div;
        const float pe = (d & 1) ? cosf(ang) : sinf(ang);
        x[(size_t)row * D + d] = emb[(size_t)t * D + d] + pe;
    }
}

// ---------------------------------------------------------------------------
// LayerNorm (D=1024): x f32 -> out bf16
// ---------------------------------------------------------------------------
__global__ __launch_bounds__(256) void layernorm_k(
    const float* __restrict__ x, const float* __restrict__ sc,
    const float* __restrict__ bi, bf16* __restrict__ out)
{
    const int D = 1024;
    const int row = blockIdx.x;
    const float* xr = x + (size_t)row * D;
    float vals[4];
    float s = 0.f, q = 0.f;
#pragma unroll
    for (int i = 0; i < 4; ++i) {
        const float v = xr[threadIdx.x + i * 256];
        vals[i] = v; s += v; q += v * v;
    }
#pragma unroll
    for (int o = 32; o; o >>= 1) { s += __shfl_xor(s, o); q += __shfl_xor(q, o); }
    __shared__ float ls[4], lq[4];
    const int w = threadIdx.x >> 6;
    if ((threadIdx.x & 63) == 0) { ls[w] = s; lq[w] = q; }
    __syncthreads();
    const float S = ls[0] + ls[1] + ls[2] + ls[3];
    const float Q = lq[0] + lq[1] + lq[2] + lq[3];
    const float mu = S * (1.0f / D);
    const float var = Q * (1.0f / D) - mu * mu;
    const float rstd = rsqrtf(var + 1e-5f);
#pragma unroll
    for (int i = 0; i < 4; ++i) {
        const int d = threadIdx.x + i * 256;
        out[(size_t)row * D + d] = (bf16)((vals[i] - mu) * rstd * sc[d] + bi[d]);
    }
}

// ---------------------------------------------------------------------------
// GEMM: C[M,N] = A[M,K](bf16) @ Bt[N,K](bf16)^T, f32 accum, various epilogues
// 128x128 tile, BK=64, 4 waves (2x2), mfma_f32_16x16x32_bf16
// EPI: 0 store bf16 | 1 Cf += acc | 2 bias+gelu->bf16 | 3 Cf += acc+bias | 4 Cf = acc+bias
// ---------------------------------------------------------------------------
template <int EPI>
__global__ __launch_bounds__(256, 2) void gemm_bt_k(
    const bf16* __restrict__ A, const bf16* __restrict__ Bt,
    float* __restrict__ Cf, bf16* __restrict__ Cb,
    const float* __restrict__ bias, int M, int N, int K)
{
    __shared__ __align__(16) bf16 Al[128 * 64];
    __shared__ __align__(16) bf16 Bl[128 * 64];
    const int tid = threadIdx.x;
    const int l = tid & 63;
    const int wbase = tid & 192;                 // wave_id * 64
    const int wr = (tid >> 7) & 1, wc = (tid >> 6) & 1;
    const int bm = blockIdx.x, bn = blockIdx.y;

    f32x4 acc[4][4];
#pragma unroll
    for (int i = 0; i < 4; ++i)
#pragma unroll
        for (int j = 0; j < 4; ++j) acc[i][j] = (f32x4){0.f, 0.f, 0.f, 0.f};

    const bf16* Abase = A + (size_t)bm * 128 * K;
    const bf16* Bbase = Bt + (size_t)bn * 128 * K;

    for (int k0 = 0; k0 < K; k0 += 64) {
        // ---- stage A and B tiles: [128 rows][64 k] bf16, XOR-swizzled slots.
        // chunk c (16B): row=c>>3 slot=c&7; global col-block = slot ^ (row&7)
#pragma unroll
        for (int i = 0; i < 4; ++i) {
            const int c = i * 256 + tid;
            const int row = c >> 3, slot = c & 7;
            const int col = ((slot ^ (row & 7)) << 3);
            __builtin_amdgcn_global_load_lds(
                GL_AS(Abase + (size_t)row * K + k0 + col),
                LDS_AS(Al + (i * 256 + wbase) * 8), 16, 0, 0);
        }
#pragma unroll
        for (int i = 0; i < 4; ++i) {
            const int c = i * 256 + tid;
            const int row = c >> 3, slot = c & 7;
            const int col = ((slot ^ (row & 7)) << 3);
            __builtin_amdgcn_global_load_lds(
                GL_AS(Bbase + (size_t)row * K + k0 + col),
                LDS_AS(Bl + (i * 256 + wbase) * 8), 16, 0, 0);
        }
        __syncthreads();   // drains vmcnt: tiles visible

#pragma unroll
        for (int ks = 0; ks < 2; ++ks) {
            bf16x8 af[4], bfr[4];
            const int kb = ks * 64 + ((l >> 4) << 4);   // byte offset of lane's k-block
#pragma unroll
            for (int mi = 0; mi < 4; ++mi) {
                const int r = wr * 64 + mi * 16 + (l & 15);
                af[mi] = *(const bf16x8*)((const char*)Al + r * 128 + (kb ^ ((r & 7) << 4)));
            }
#pragma unroll
            for (int ni = 0; ni < 4; ++ni) {
                const int r = wc * 64 + ni * 16 + (l & 15);
                bfr[ni] = *(const bf16x8*)((const char*)Bl + r * 128 + (kb ^ ((r & 7) << 4)));
            }
#pragma unroll
            for (int mi = 0; mi < 4; ++mi)
#pragma unroll
                for (int ni = 0; ni < 4; ++ni)
                    acc[mi][ni] = __builtin_amdgcn_mfma_f32_16x16x32_bf16(
                        af[mi], bfr[ni], acc[mi][ni], 0, 0, 0);
        }
        __syncthreads();   // all reads done before next stage overwrites
    }

    // ---- epilogue: C/D layout col=lane&15, row=(lane>>4)*4+j  [m89/m91]
    const int colb = bn * 128 + wc * 64;
    const int rowb = bm * 128 + wr * 64 + ((l >> 4) << 2);
#pragma unroll
    for (int mi = 0; mi < 4; ++mi) {
#pragma unroll
        for (int ni = 0; ni < 4; ++ni) {
            const int col = colb + ni * 16 + (l & 15);
#pragma unroll
            for (int j = 0; j < 4; ++j) {
                const int row = rowb + mi * 16 + j;
                const float v = acc[mi][ni][j];
                if constexpr (EPI == 0) {
                    Cb[(size_t)row * N + col] = (bf16)v;
                } else if constexpr (EPI == 1) {
                    Cf[(size_t)row * N + col] += v;
                } else if constexpr (EPI == 2) {
                    const float u = v + bias[col];
                    const float g = 0.5f * u * (1.0f + erff(u * 0.70710678118654752f));
                    Cb[(size_t)row * N + col] = (bf16)g;
                } else if constexpr (EPI == 3) {
                    Cf[(size_t)row * N + col] += v + bias[col];
                } else {
                    Cf[(size_t)row * N + col] = v + bias[col];
                }
            }
        }
    }
}

// ---------------------------------------------------------------------------
// MFMA flash attention v2. 4 waves per block, 64 q-rows per block (16/wave).
// K/V tiles (32 keys) staged cooperatively into double-buffered swizzled LDS,
// one tile ahead (global_load_lds overlaps compute; __syncthreads publishes).
// grid.x = B*H*(S/64) = 512.  qkv bf16 [B*S, 3072]: q at h*64+d, k at 1024+h*64+d.
// vt bf16 [B][1024 hd][1024 s] (pre-transposed V).  out o bf16 [B*S, 1024].
//
// Fragment conventions (proven by gemm_bt_k, m89/m91):
//   A-frag: lane l holds A[l&15][(l>>4)*8 + jj]   (8 contiguous k)
//   B-frag: lane l holds B[(l>>4)*8 + jj][l&15]
//   C:      lane l holds C[(l>>4)*4 + j][l&15]
// ---------------------------------------------------------------------------
__global__ __launch_bounds__(256) void attn_mfma_k(
    const bf16* __restrict__ qkv, const bf16* __restrict__ vt,
    bf16* __restrict__ o)
{
    // K tile: [32 kv-rows][64 d] bf16, 128 B/row, 8 slots of 16B, slot ^= (row&7)
    // V tile: [64 d-rows][32 s] bf16,  64 B/row, 4 slots of 16B, slot ^= (row>>1)&3
    __shared__ __align__(16) bf16 Kl[2][32 * 64];
    __shared__ __align__(16) bf16 Vl[2][64 * 32];
    __shared__ __align__(16) bf16 Pl[4][16][88];   // per-wave P round-trip

    const int tid = threadIdx.x;
    const int w = tid >> 6, l = tid & 63;
    const int g = l >> 4, lc = l & 15;
    const int qt = blockIdx.x & 15;      // S/64 = 16 q-blocks
    const int bh = blockIdx.x >> 4;
    const int h = bh & 15, b = bh >> 4;
    const int q0 = qt * 64;
    const int qw = q0 + w * 16;          // this wave's q-subtile
    const int diag = qw >> 5;            // wave's diagonal (masked) tile
    const int NT = (q0 >> 5) + 2;        // tiles staged by this block

    const bf16* qbase = qkv + (size_t)b * 1024 * 3072 + h * 64;
    const bf16* kbase = qbase + 1024;
    const bf16* vbase = vt + (size_t)(b * 16 + h) * 64 * 1024;

    // Q A-frags: lane holds Q[qw+lc][c*32 + g*8 + jj]
    bf16x8 af0, af1;
    {
        const bf16* qp = qbase + (size_t)(qw + lc) * 3072 + g * 8;
        af0 = *(const bf16x8*)qp;
        af1 = *(const bf16x8*)(qp + 32);
    }

    f32x4 acc[4];                        // O: rows qw+4g+j, cols dt*16+lc
#pragma unroll
    for (int dt = 0; dt < 4; ++dt) acc[dt] = (f32x4){0.f, 0.f, 0.f, 0.f};
    f32x4 m  = (f32x4){-1e30f, -1e30f, -1e30f, -1e30f};
    f32x4 ls = (f32x4){0.f, 0.f, 0.f, 0.f};   // lane-partial row sums

    // cooperative stage of tile t (256 threads, 1 chunk each per matrix)
    auto stage = [&](int t) {
        const int k0 = t * 32;
        const int buf = t & 1;
        {   // K: chunk=tid -> row=tid>>3, slot=tid&7; src d-octet = slot^(row&7)
            const int row = tid >> 3;
            const int d = (((tid & 7) ^ (row & 7)) << 3);
            __builtin_amdgcn_global_load_lds(
                GL_AS(kbase + (size_t)(k0 + row) * 3072 + d),
                LDS_AS(Kl[buf] + (tid & 192) * 8), 16, 0, 0);
        }
        {   // V: chunk=tid -> row=tid>>2 (d), slot=tid&3; src s-octet = slot^((row>>1)&3)
            const int row = tid >> 2;
            const int s = (((tid & 3) ^ ((tid >> 3) & 3)) << 3);
            __builtin_amdgcn_global_load_lds(
                GL_AS(vbase + (size_t)row * 1024 + k0 + s),
                LDS_AS(Vl[buf] + (tid & 192) * 8), 16, 0, 0);
        }
    };

    auto compute = [&](int t, bool MASKED) {
        const char* KT = (const char*)Kl[t & 1];
        const char* VT = (const char*)Vl[t & 1];
        const int k0 = t * 32;

        // K B-frags from LDS (swizzled): kfXY: X = key-half, Y = d-half
        const int r0 = lc, r1 = 16 + lc;
        const bf16x8 kf00 = *(const bf16x8*)(KT + r0 * 128 + 16 * (g       ^ (r0 & 7)));
        const bf16x8 kf01 = *(const bf16x8*)(KT + r0 * 128 + 16 * ((4 + g) ^ (r0 & 7)));
        const bf16x8 kf10 = *(const bf16x8*)(KT + r1 * 128 + 16 * (g       ^ (r1 & 7)));
        const bf16x8 kf11 = *(const bf16x8*)(KT + r1 * 128 + 16 * ((4 + g) ^ (r1 & 7)));

        f32x4 s0 = (f32x4){0.f, 0.f, 0.f, 0.f};
        f32x4 s1 = (f32x4){0.f, 0.f, 0.f, 0.f};
        s0 = __builtin_amdgcn_mfma_f32_16x16x32_bf16(af0, kf00, s0, 0, 0, 0);
        s0 = __builtin_amdgcn_mfma_f32_16x16x32_bf16(af1, kf01, s0, 0, 0, 0);
        s1 = __builtin_amdgcn_mfma_f32_16x16x32_bf16(af0, kf10, s1, 0, 0, 0);
        s1 = __builtin_amdgcn_mfma_f32_16x16x32_bf16(af1, kf11, s1, 0, 0, 0);

        // scale (+ causal mask on the diagonal tile)
#pragma unroll
        for (int j = 0; j < 4; ++j) {
            if (MASKED) {
                const int row = qw + 4 * g + j;
                s0[j] = (k0 + lc <= row)      ? s0[j] * 0.125f : -1e30f;
                s1[j] = (k0 + 16 + lc <= row) ? s1[j] * 0.125f : -1e30f;
            } else {
                s0[j] *= 0.125f;
                s1[j] *= 0.125f;
            }
        }

        // row-max across the 16 lanes of this group (cols) + both key-halves
        f32x4 tmx;
#pragma unroll
        for (int j = 0; j < 4; ++j) tmx[j] = fmaxf(s0[j], s1[j]);
#pragma unroll
        for (int off = 8; off; off >>= 1)
#pragma unroll
            for (int j = 0; j < 4; ++j) tmx[j] = fmaxf(tmx[j], __shfl_xor(tmx[j], off));

        f32x4 sc, p0, p1;
#pragma unroll
        for (int j = 0; j < 4; ++j) {
            const float mn = fmaxf(m[j], tmx[j]);
            sc[j] = __expf(m[j] - mn);
            p0[j] = __expf(s0[j] - mn);
            p1[j] = __expf(s1[j] - mn);
            m[j] = mn;
            ls[j] = ls[j] * sc[j] + p0[j] + p1[j];
        }
#pragma unroll
        for (int dt = 0; dt < 4; ++dt)
#pragma unroll
            for (int j = 0; j < 4; ++j) acc[dt][j] *= sc[j];

        // P -> LDS in C-layout; read back in A-frag layout. hi/lo bf16 split
        // keeps P at ~24-bit accuracy.
#pragma unroll
        for (int j = 0; j < 4; ++j) {
            const int r = 4 * g + j;
            const bf16 h0 = (bf16)p0[j];
            const bf16 h1 = (bf16)p1[j];
            Pl[w][r][lc]      = h0;
            Pl[w][r][16 + lc] = h1;
            Pl[w][r][48 + lc] = (bf16)(p0[j] - (float)h0);
            Pl[w][r][64 + lc] = (bf16)(p1[j] - (float)h1);
        }
        const bf16x8 pah = *(const bf16x8*)&Pl[w][lc][g * 8];
        const bf16x8 pal = *(const bf16x8*)&Pl[w][lc][48 + g * 8];

        // PV: B-frag of V^T from swizzled LDS tile
#pragma unroll
        for (int dt = 0; dt < 4; ++dt) {
            const int vr = dt * 16 + lc;
            const bf16x8 vf = *(const bf16x8*)(VT + vr * 64 + 16 * (g ^ ((vr >> 1) & 3)));
            acc[dt] = __builtin_amdgcn_mfma_f32_16x16x32_bf16(pah, vf, acc[dt], 0, 0, 0);
            acc[dt] = __builtin_amdgcn_mfma_f32_16x16x32_bf16(pal, vf, acc[dt], 0, 0, 0);
        }
    };

    stage(0);
    __syncthreads();                       // vmcnt drain: tile 0 visible
    for (int t = 0; t < NT; ++t) {
        if (t + 1 < NT) stage(t + 1);      // async into the other buffer
        if (t <= diag) compute(t, t == diag);
        __syncthreads();                   // publish tile t+1; reads of t done
    }

    // reduce lane-partial row sums across the 16 cols, normalize, store
    f32x4 inv;
#pragma unroll
    for (int j = 0; j < 4; ++j) {
        float s = ls[j];
#pragma unroll
        for (int off = 8; off; off >>= 1) s += __shfl_xor(s, off);
        inv[j] = 1.0f / s;
    }
    bf16* op = o + (size_t)(b * 1024 + qw) * 1024 + h * 64;
#pragma unroll
    for (int dt = 0; dt < 4; ++dt)
#pragma unroll
        for (int j = 0; j < 4; ++j)
            op[(size_t)(4 * g + j) * 1024 + dt * 16 + lc] = (bf16)(acc[dt][j] * inv[j]);
}

// ---------------------------------------------------------------------------
extern "C" void kernel_launch(void* const* d_in, const int* in_sizes, int n_in,
                              void* d_out, int out_size, void* d_ws, size_t ws_size,
                              hipStream_t stream)
{
    const int B = 2, S = 1024, D = 1024, L = 6, F = 4096, V = 32000, H = 16;
    const int M = B * S;

    const int*   tokens    = (const int*)  d_in[0];
    const float* token_emb = (const float*)d_in[1];
    const float* Wqkv      = (const float*)d_in[2];
    const float* Wout      = (const float*)d_in[3];
    const float* ln1_s     = (const float*)d_in[4];
    const float* ln1_b     = (const float*)d_in[5];
    const float* W1        = (const float*)d_in[6];
    const float* b1        = (const float*)d_in[7];
    const float* W2        = (const float*)d_in[8];
    const float* b2        = (const float*)d_in[9];
    const float* ln2_s     = (const float*)d_in[10];
    const float* ln2_b     = (const float*)d_in[11];
    const float* lnf_s     = (const float*)d_in[12];
    const float* lnf_b     = (const float*)d_in[13];
    const float* Whead     = (const float*)d_in[14];
    const float* bhead     = (const float*)d_in[15];
    float* out = (float*)d_out;

    char* w = (char*)d_ws;
    size_t off = 0;
    auto alloc = [&](size_t n) { char* p = w + off; off += (n + 255) & ~(size_t)255; return p; };
    bf16* WqkvT  = (bf16*)alloc((size_t)L * 3 * D * D * 2);
    bf16* WoutT  = (bf16*)alloc((size_t)L * D * D * 2);
    bf16* W1T    = (bf16*)alloc((size_t)L * F * D * 2);
    bf16* W2T    = (bf16*)alloc((size_t)L * D * F * 2);
    bf16* WheadT = (bf16*)alloc((size_t)V * D * 2);
    float* x     = (float*)alloc((size_t)M * D * 4);
    bf16* h      = (bf16*)alloc((size_t)M * D * 2);
    bf16* qkv    = (bf16*)alloc((size_t)M * 3 * D * 2);
    bf16* ob     = (bf16*)alloc((size_t)M * D * 2);
    bf16* mid    = (bf16*)alloc((size_t)M * F * 2);
    // vt aliases mid: vt is live only qkv-GEMM -> attn; mid only W1 -> W2.
    bf16* vt     = mid;   // [B][1024 hd][1024 s] = 4 MB <= 16.8 MB

    const dim3 tb(32, 8);
    transpose_cast_k<<<dim3(3 * D / 32, D / 32, L), tb, 0, stream>>>(Wqkv, WqkvT, D, 3 * D);
    transpose_cast_k<<<dim3(D / 32, D / 32, L),     tb, 0, stream>>>(Wout, WoutT, D, D);
    transpose_cast_k<<<dim3(F / 32, D / 32, L),     tb, 0, stream>>>(W1, W1T, D, F);
    transpose_cast_k<<<dim3(D / 32, F / 32, L),     tb, 0, stream>>>(W2, W2T, F, D);
    transpose_cast_k<<<dim3(V / 32, D / 32, 1),     tb, 0, stream>>>(Whead, WheadT, D, V);

    embed_k<<<M, 256, 0, stream>>>(tokens, token_emb, x);

    for (int lyr = 0; lyr < L; ++lyr) {
        layernorm_k<<<M, 256, 0, stream>>>(x, ln1_s + lyr * D, ln1_b + lyr * D, h);
        gemm_bt_k<0><<<dim3(M / 128, 3 * D / 128), 256, 0, stream>>>(
            h, WqkvT + (size_t)lyr * 3 * D * D, nullptr, qkv, nullptr, M, 3 * D, D);
        vtrans_k<<<dim3(D / 32, S / 32, B), tb, 0, stream>>>(qkv, vt);
        attn_mfma_k<<<B * H * S / 64, 256, 0, stream>>>(qkv, vt, ob);
        gemm_bt_k<1><<<dim3(M / 128, D / 128), 256, 0, stream>>>(
            ob, WoutT + (size_t)lyr * D * D, x, nullptr, nullptr, M, D, D);
        layernorm_k<<<M, 256, 0, stream>>>(x, ln2_s + lyr * D, ln2_b + lyr * D, h);
        gemm_bt_k<2><<<dim3(M / 128, F / 128), 256, 0, stream>>>(
            h, W1T + (size_t)lyr * F * D, nullptr, mid, b1 + lyr * F, M, F, D);
        gemm_bt_k<3><<<dim3(M / 128, D / 128), 256, 0, stream>>>(
            mid, W2T + (size_t)lyr * D * F, x, nullptr, b2 + lyr * D, M, D, F);
    }
    layernorm_k<<<M, 256, 0, stream>>>(x, lnf_s, lnf_b, h);
    gemm_bt_k<4><<<dim3(M / 128, V / 128), 256, 0, stream>>>(
        h, WheadT, out, nullptr, bhead, M, V, D);
}

// Round 3
// 1582.356 us; speedup vs baseline: 6.9588x; 1.1023x over previous
//
#include <hip/hip_runtime.h>
#include <hip/hip_bf16.h>
#include <math.h>

typedef __bf16 bf16;
typedef __bf16 bf16x8 __attribute__((ext_vector_type(8)));
typedef float f32x4 __attribute__((ext_vector_type(4)));

#define GL_AS(p) ((const __attribute__((address_space(1))) void*)(p))
#define LDS_AS(p) ((__attribute__((address_space(3))) void*)(p))

// ---------------------------------------------------------------------------
// Transpose + f32->bf16 cast:  in [R,C] f32 (batched on z)  ->  out [C,R] bf16
// ---------------------------------------------------------------------------
__global__ __launch_bounds__(256) void transpose_cast_k(
    const float* __restrict__ in, bf16* __restrict__ out, int R, int C)
{
    __shared__ float t[32][33];
    const int c0 = blockIdx.x * 32, r0 = blockIdx.y * 32;
    const size_t zoff = (size_t)blockIdx.z * R * C;
    const float* inb = in + zoff;
    bf16* outb = out + zoff;
    const int tx = threadIdx.x, ty = threadIdx.y;   // (32, 8)
#pragma unroll
    for (int i = 0; i < 32; i += 8)
        t[ty + i][tx] = inb[(size_t)(r0 + ty + i) * C + c0 + tx];
    __syncthreads();
#pragma unroll
    for (int i = 0; i < 32; i += 8)
        outb[(size_t)(c0 + ty + i) * R + r0 + tx] = (bf16)t[tx][ty + i];
}

// ---------------------------------------------------------------------------
// Embedding + sinusoidal positional encoding -> x f32 [B*S, 1024]
// ---------------------------------------------------------------------------
__global__ __launch_bounds__(256) void embed_k(
    const int* __restrict__ tok, const float* __restrict__ emb,
    float* __restrict__ x)
{
    const int D = 1024;
    const int row = blockIdx.x;
    const int s = row & 1023;          // S = 1024
    const int t = tok[row];
#pragma unroll
    for (int i = 0; i < 4; ++i) {
        const int d = threadIdx.x + i * 256;
        const int half = d >> 1;
        const float div = expf(-(float)half * (9.210340371976184f / 512.0f));
        const float ang = (float)s * div;
        const float pe = (d & 1) ? cosf(ang) : sinf(ang);
        x[(size_t)row * D + d] = emb[(size_t)t * D + d] + pe;
    }
}

// ---------------------------------------------------------------------------
// LayerNorm (D=1024): x f32 -> out bf16
// ---------------------------------------------------------------------------
__global__ __launch_bounds__(256) void layernorm_k(
    const float* __restrict__ x, const float* __restrict__ sc,
    const float* __restrict__ bi, bf16* __restrict__ out)
{
    const int D = 1024;
    const int row = blockIdx.x;
    const float* xr = x + (size_t)row * D;
    float vals[4];
    float s = 0.f, q = 0.f;
#pragma unroll
    for (int i = 0; i < 4; ++i) {
        const float v = xr[threadIdx.x + i * 256];
        vals[i] = v; s += v; q += v * v;
    }
#pragma unroll
    for (int o = 32; o; o >>= 1) { s += __shfl_xor(s, o); q += __shfl_xor(q, o); }
    __shared__ float ls[4], lq[4];
    const int w = threadIdx.x >> 6;
    if ((threadIdx.x & 63) == 0) { ls[w] = s; lq[w] = q; }
    __syncthreads();
    const float S = ls[0] + ls[1] + ls[2] + ls[3];
    const float Q = lq[0] + lq[1] + lq[2] + lq[3];
    const float mu = S * (1.0f / D);
    const float var = Q * (1.0f / D) - mu * mu;
    const float rstd = rsqrtf(var + 1e-5f);
#pragma unroll
    for (int i = 0; i < 4; ++i) {
        const int d = threadIdx.x + i * 256;
        out[(size_t)row * D + d] = (bf16)((vals[i] - mu) * rstd * sc[d] + bi[d]);
    }
}

// ---------------------------------------------------------------------------
// GEMM: C[M,N] = A[M,K](bf16) @ Bt[N,K](bf16)^T, f32 accum, various epilogues
// 128x128 tile, BK=64, 4 waves (2x2), mfma_f32_16x16x32_bf16
// EPI: 0 store bf16 | 1 Cf += acc (atomic if SK>1) | 2 bias+gelu->bf16
//      3 Cf += acc+bias (atomic if SK>1) | 4 Cf = acc+bias (nontemporal)
//      5 qkv write: cols<2048 -> Cb, cols>=2048 -> Cb2 = vt[b][hd][s]
// SK: split-K factor (blockIdx.z = K-slice)
// ---------------------------------------------------------------------------
template <int EPI, int SK = 1>
__global__ __launch_bounds__(256, 2) void gemm_bt_k(
    const bf16* __restrict__ A, const bf16* __restrict__ Bt,
    float* __restrict__ Cf, bf16* __restrict__ Cb, bf16* __restrict__ Cb2,
    const float* __restrict__ bias, int M, int N, int K)
{
    __shared__ __align__(16) bf16 Al[128 * 64];
    __shared__ __align__(16) bf16 Bl[128 * 64];
    const int tid = threadIdx.x;
    const int l = tid & 63;
    const int wbase = tid & 192;                 // wave_id * 64
    const int wr = (tid >> 7) & 1, wc = (tid >> 6) & 1;
    const int bm = blockIdx.x, bn = blockIdx.y;
    const int kz = blockIdx.z;
    const int Kc = K / SK;                       // this slice's K extent

    f32x4 acc[4][4];
#pragma unroll
    for (int i = 0; i < 4; ++i)
#pragma unroll
        for (int j = 0; j < 4; ++j) acc[i][j] = (f32x4){0.f, 0.f, 0.f, 0.f};

    const bf16* Abase = A + (size_t)bm * 128 * K + (size_t)kz * Kc;
    const bf16* Bbase = Bt + (size_t)bn * 128 * K + (size_t)kz * Kc;

    for (int k0 = 0; k0 < Kc; k0 += 64) {
        // ---- stage A and B tiles: [128 rows][64 k] bf16, XOR-swizzled slots.
        // chunk c (16B): row=c>>3 slot=c&7; global col-block = slot ^ (row&7)
#pragma unroll
        for (int i = 0; i < 4; ++i) {
            const int c = i * 256 + tid;
            const int row = c >> 3, slot = c & 7;
            const int col = ((slot ^ (row & 7)) << 3);
            __builtin_amdgcn_global_load_lds(
                GL_AS(Abase + (size_t)row * K + k0 + col),
                LDS_AS(Al + (i * 256 + wbase) * 8), 16, 0, 0);
        }
#pragma unroll
        for (int i = 0; i < 4; ++i) {
            const int c = i * 256 + tid;
            const int row = c >> 3, slot = c & 7;
            const int col = ((slot ^ (row & 7)) << 3);
            __builtin_amdgcn_global_load_lds(
                GL_AS(Bbase + (size_t)row * K + k0 + col),
                LDS_AS(Bl + (i * 256 + wbase) * 8), 16, 0, 0);
        }
        __syncthreads();   // drains vmcnt: tiles visible

#pragma unroll
        for (int ks = 0; ks < 2; ++ks) {
            bf16x8 af[4], bfr[4];
            const int kb = ks * 64 + ((l >> 4) << 4);   // byte offset of lane's k-block
#pragma unroll
            for (int mi = 0; mi < 4; ++mi) {
                const int r = wr * 64 + mi * 16 + (l & 15);
                af[mi] = *(const bf16x8*)((const char*)Al + r * 128 + (kb ^ ((r & 7) << 4)));
            }
#pragma unroll
            for (int ni = 0; ni < 4; ++ni) {
                const int r = wc * 64 + ni * 16 + (l & 15);
                bfr[ni] = *(const bf16x8*)((const char*)Bl + r * 128 + (kb ^ ((r & 7) << 4)));
            }
#pragma unroll
            for (int mi = 0; mi < 4; ++mi)
#pragma unroll
                for (int ni = 0; ni < 4; ++ni)
                    acc[mi][ni] = __builtin_amdgcn_mfma_f32_16x16x32_bf16(
                        af[mi], bfr[ni], acc[mi][ni], 0, 0, 0);
        }
        __syncthreads();   // all reads done before next stage overwrites
    }

    // ---- epilogue: C/D layout col=lane&15, row=(lane>>4)*4+j  [m89/m91]
    const int colb = bn * 128 + wc * 64;
    const int rowb = bm * 128 + wr * 64 + ((l >> 4) << 2);
#pragma unroll
    for (int mi = 0; mi < 4; ++mi) {
#pragma unroll
        for (int ni = 0; ni < 4; ++ni) {
            const int col = colb + ni * 16 + (l & 15);
#pragma unroll
            for (int j = 0; j < 4; ++j) {
                const int row = rowb + mi * 16 + j;
                const float v = acc[mi][ni][j];
                if constexpr (EPI == 0) {
                    Cb[(size_t)row * N + col] = (bf16)v;
                } else if constexpr (EPI == 1) {
                    if constexpr (SK > 1) atomicAdd(&Cf[(size_t)row * N + col], v);
                    else                  Cf[(size_t)row * N + col] += v;
                } else if constexpr (EPI == 2) {
                    const float u = v + bias[col];
                    const float g = 0.5f * u * (1.0f + erff(u * 0.70710678118654752f));
                    Cb[(size_t)row * N + col] = (bf16)g;
                } else if constexpr (EPI == 3) {
                    const float add = (SK == 1 || kz == 0) ? v + bias[col] : v;
                    if constexpr (SK > 1) atomicAdd(&Cf[(size_t)row * N + col], add);
                    else                  Cf[(size_t)row * N + col] += add;
                } else if constexpr (EPI == 4) {
                    __builtin_nontemporal_store(v + bias[col], &Cf[(size_t)row * N + col]);
                } else {   // EPI == 5: qkv write with V folded out to vt
                    if (col < 2048) {
                        Cb[(size_t)row * N + col] = (bf16)v;
                    } else {
                        // vt[b][hd][s]: b*1024 = row & ~1023, hd = col-2048, s = row & 1023
                        Cb2[((size_t)(row & ~1023) + (col - 2048)) * 1024 + (row & 1023)] = (bf16)v;
                    }
                }
            }
        }
    }
}

// ---------------------------------------------------------------------------
// MFMA flash attention v2. 4 waves per block, 64 q-rows per block (16/wave).
// K/V tiles (32 keys) staged cooperatively into double-buffered swizzled LDS,
// one tile ahead (global_load_lds overlaps compute; __syncthreads publishes).
// grid.x = B*H*(S/64) = 512.  qkv bf16 [B*S, 3072]: q at h*64+d, k at 1024+h*64+d.
// vt bf16 [B][1024 hd][1024 s] (pre-transposed V).  out o bf16 [B*S, 1024].
//
// Fragment conventions (proven by gemm_bt_k, m89/m91):
//   A-frag: lane l holds A[l&15][(l>>4)*8 + jj]   (8 contiguous k)
//   B-frag: lane l holds B[(l>>4)*8 + jj][l&15]
//   C:      lane l holds C[(l>>4)*4 + j][l&15]
// ---------------------------------------------------------------------------
__global__ __launch_bounds__(256) void attn_mfma_k(
    const bf16* __restrict__ qkv, const bf16* __restrict__ vt,
    bf16* __restrict__ o)
{
    // K tile: [32 kv-rows][64 d] bf16, 128 B/row, 8 slots of 16B, slot ^= (row&7)
    // V tile: [64 d-rows][32 s] bf16,  64 B/row, 4 slots of 16B, slot ^= (row>>1)&3
    __shared__ __align__(16) bf16 Kl[2][32 * 64];
    __shared__ __align__(16) bf16 Vl[2][64 * 32];
    __shared__ __align__(16) bf16 Pl[4][16][88];   // per-wave P round-trip

    const int tid = threadIdx.x;
    const int w = tid >> 6, l = tid & 63;
    const int g = l >> 4, lc = l & 15;
    const int qt = blockIdx.x & 15;      // S/64 = 16 q-blocks
    const int bh = blockIdx.x >> 4;
    const int h = bh & 15, b = bh >> 4;
    const int q0 = qt * 64;
    const int qw = q0 + w * 16;          // this wave's q-subtile
    const int diag = qw >> 5;            // wave's diagonal (masked) tile
    const int NT = (q0 >> 5) + 2;        // tiles staged by this block

    const bf16* qbase = qkv + (size_t)b * 1024 * 3072 + h * 64;
    const bf16* kbase = qbase + 1024;
    const bf16* vbase = vt + (size_t)(b * 16 + h) * 64 * 1024;

    // Q A-frags: lane holds Q[qw+lc][c*32 + g*8 + jj]
    bf16x8 af0, af1;
    {
        const bf16* qp = qbase + (size_t)(qw + lc) * 3072 + g * 8;
        af0 = *(const bf16x8*)qp;
        af1 = *(const bf16x8*)(qp + 32);
    }

    f32x4 acc[4];                        // O: rows qw+4g+j, cols dt*16+lc
#pragma unroll
    for (int dt = 0; dt < 4; ++dt) acc[dt] = (f32x4){0.f, 0.f, 0.f, 0.f};
    f32x4 m  = (f32x4){-1e30f, -1e30f, -1e30f, -1e30f};
    f32x4 ls = (f32x4){0.f, 0.f, 0.f, 0.f};   // lane-partial row sums

    // cooperative stage of tile t (256 threads, 1 chunk each per matrix)
    auto stage = [&](int t) {
        const int k0 = t * 32;
        const int buf = t & 1;
        {   // K: chunk=tid -> row=tid>>3, slot=tid&7; src d-octet = slot^(row&7)
            const int row = tid >> 3;
            const int d = (((tid & 7) ^ (row & 7)) << 3);
            __builtin_amdgcn_global_load_lds(
                GL_AS(kbase + (size_t)(k0 + row) * 3072 + d),
                LDS_AS(Kl[buf] + (tid & 192) * 8), 16, 0, 0);
        }
        {   // V: chunk=tid -> row=tid>>2 (d), slot=tid&3; src s-octet = slot^((row>>1)&3)
            const int row = tid >> 2;
            const int s = (((tid & 3) ^ ((tid >> 3) & 3)) << 3);
            __builtin_amdgcn_global_load_lds(
                GL_AS(vbase + (size_t)row * 1024 + k0 + s),
                LDS_AS(Vl[buf] + (tid & 192) * 8), 16, 0, 0);
        }
    };

    auto compute = [&](int t, bool MASKED) {
        const char* KT = (const char*)Kl[t & 1];
        const char* VT = (const char*)Vl[t & 1];
        const int k0 = t * 32;

        // K B-frags from LDS (swizzled): kfXY: X = key-half, Y = d-half
        const int r0 = lc, r1 = 16 + lc;
        const bf16x8 kf00 = *(const bf16x8*)(KT + r0 * 128 + 16 * (g       ^ (r0 & 7)));
        const bf16x8 kf01 = *(const bf16x8*)(KT + r0 * 128 + 16 * ((4 + g) ^ (r0 & 7)));
        const bf16x8 kf10 = *(const bf16x8*)(KT + r1 * 128 + 16 * (g       ^ (r1 & 7)));
        const bf16x8 kf11 = *(const bf16x8*)(KT + r1 * 128 + 16 * ((4 + g) ^ (r1 & 7)));

        f32x4 s0 = (f32x4){0.f, 0.f, 0.f, 0.f};
        f32x4 s1 = (f32x4){0.f, 0.f, 0.f, 0.f};
        s0 = __builtin_amdgcn_mfma_f32_16x16x32_bf16(af0, kf00, s0, 0, 0, 0);
        s0 = __builtin_amdgcn_mfma_f32_16x16x32_bf16(af1, kf01, s0, 0, 0, 0);
        s1 = __builtin_amdgcn_mfma_f32_16x16x32_bf16(af0, kf10, s1, 0, 0, 0);
        s1 = __builtin_amdgcn_mfma_f32_16x16x32_bf16(af1, kf11, s1, 0, 0, 0);

        // scale (+ causal mask on the diagonal tile)
#pragma unroll
        for (int j = 0; j < 4; ++j) {
            if (MASKED) {
                const int row = qw + 4 * g + j;
                s0[j] = (k0 + lc <= row)      ? s0[j] * 0.125f : -1e30f;
                s1[j] = (k0 + 16 + lc <= row) ? s1[j] * 0.125f : -1e30f;
            } else {
                s0[j] *= 0.125f;
                s1[j] *= 0.125f;
            }
        }

        // row-max across the 16 lanes of this group (cols) + both key-halves
        f32x4 tmx;
#pragma unroll
        for (int j = 0; j < 4; ++j) tmx[j] = fmaxf(s0[j], s1[j]);
#pragma unroll
        for (int off = 8; off; off >>= 1)
#pragma unroll
            for (int j = 0; j < 4; ++j) tmx[j] = fmaxf(tmx[j], __shfl_xor(tmx[j], off));

        f32x4 sc, p0, p1;
#pragma unroll
        for (int j = 0; j < 4; ++j) {
            const float mn = fmaxf(m[j], tmx[j]);
            sc[j] = __expf(m[j] - mn);
            p0[j] = __expf(s0[j] - mn);
            p1[j] = __expf(s1[j] - mn);
            m[j] = mn;
            ls[j] = ls[j] * sc[j] + p0[j] + p1[j];
        }
#pragma unroll
        for (int dt = 0; dt < 4; ++dt)
#pragma unroll
            for (int j = 0; j < 4; ++j) acc[dt][j] *= sc[j];

        // P -> LDS in C-layout; read back in A-frag layout. hi/lo bf16 split
        // keeps P at ~24-bit accuracy.
#pragma unroll
        for (int j = 0; j < 4; ++j) {
            const int r = 4 * g + j;
            const bf16 h0 = (bf16)p0[j];
            const bf16 h1 = (bf16)p1[j];
            Pl[w][r][lc]      = h0;
            Pl[w][r][16 + lc] = h1;
            Pl[w][r][48 + lc] = (bf16)(p0[j] - (float)h0);
            Pl[w][r][64 + lc] = (bf16)(p1[j] - (float)h1);
        }
        const bf16x8 pah = *(const bf16x8*)&Pl[w][lc][g * 8];
        const bf16x8 pal = *(const bf16x8*)&Pl[w][lc][48 + g * 8];

        // PV: B-frag of V^T from swizzled LDS tile
#pragma unroll
        for (int dt = 0; dt < 4; ++dt) {
            const int vr = dt * 16 + lc;
            const bf16x8 vf = *(const bf16x8*)(VT + vr * 64 + 16 * (g ^ ((vr >> 1) & 3)));
            acc[dt] = __builtin_amdgcn_mfma_f32_16x16x32_bf16(pah, vf, acc[dt], 0, 0, 0);
            acc[dt] = __builtin_amdgcn_mfma_f32_16x16x32_bf16(pal, vf, acc[dt], 0, 0, 0);
        }
    };

    stage(0);
    __syncthreads();                       // vmcnt drain: tile 0 visible
    for (int t = 0; t < NT; ++t) {
        if (t + 1 < NT) stage(t + 1);      // async into the other buffer
        if (t <= diag) compute(t, t == diag);
        __syncthreads();                   // publish tile t+1; reads of t done
    }

    // reduce lane-partial row sums across the 16 cols, normalize, store
    f32x4 inv;
#pragma unroll
    for (int j = 0; j < 4; ++j) {
        float s = ls[j];
#pragma unroll
        for (int off = 8; off; off >>= 1) s += __shfl_xor(s, off);
        inv[j] = 1.0f / s;
    }
    bf16* op = o + (size_t)(b * 1024 + qw) * 1024 + h * 64;
#pragma unroll
    for (int dt = 0; dt < 4; ++dt)
#pragma unroll
        for (int j = 0; j < 4; ++j)
            op[(size_t)(4 * g + j) * 1024 + dt * 16 + lc] = (bf16)(acc[dt][j] * inv[j]);
}

// ---------------------------------------------------------------------------
extern "C" void kernel_launch(void* const* d_in, const int* in_sizes, int n_in,
                              void* d_out, int out_size, void* d_ws, size_t ws_size,
                              hipStream_t stream)
{
    const int B = 2, S = 1024, D = 1024, L = 6, F = 4096, V = 32000, H = 16;
    const int M = B * S;

    const int*   tokens    = (const int*)  d_in[0];
    const float* token_emb = (const float*)d_in[1];
    const float* Wqkv      = (const float*)d_in[2];
    const float* Wout      = (const float*)d_in[3];
    const float* ln1_s     = (const float*)d_in[4];
    const float* ln1_b     = (const float*)d_in[5];
    const float* W1        = (const float*)d_in[6];
    const float* b1        = (const float*)d_in[7];
    const float* W2        = (const float*)d_in[8];
    const float* b2        = (const float*)d_in[9];
    const float* ln2_s     = (const float*)d_in[10];
    const float* ln2_b     = (const float*)d_in[11];
    const float* lnf_s     = (const float*)d_in[12];
    const float* lnf_b     = (const float*)d_in[13];
    const float* Whead     = (const float*)d_in[14];
    const float* bhead     = (const float*)d_in[15];
    float* out = (float*)d_out;

    char* w = (char*)d_ws;
    size_t off = 0;
    auto alloc = [&](size_t n) { char* p = w + off; off += (n + 255) & ~(size_t)255; return p; };
    bf16* WqkvT  = (bf16*)alloc((size_t)L * 3 * D * D * 2);
    bf16* WoutT  = (bf16*)alloc((size_t)L * D * D * 2);
    bf16* W1T    = (bf16*)alloc((size_t)L * F * D * 2);
    bf16* W2T    = (bf16*)alloc((size_t)L * D * F * 2);
    bf16* WheadT = (bf16*)alloc((size_t)V * D * 2);
    float* x     = (float*)alloc((size_t)M * D * 4);
    bf16* h      = (bf16*)alloc((size_t)M * D * 2);
    bf16* qkv    = (bf16*)alloc((size_t)M * 3 * D * 2);
    bf16* ob     = (bf16*)alloc((size_t)M * D * 2);
    bf16* mid    = (bf16*)alloc((size_t)M * F * 2);
    // vt aliases mid: vt is live only qkv-GEMM -> attn; mid only W1 -> W2.
    bf16* vt     = mid;   // [B][1024 hd][1024 s] = 4 MB <= 16.8 MB

    const dim3 tb(32, 8);
    transpose_cast_k<<<dim3(3 * D / 32, D / 32, L), tb, 0, stream>>>(Wqkv, WqkvT, D, 3 * D);
    transpose_cast_k<<<dim3(D / 32, D / 32, L),     tb, 0, stream>>>(Wout, WoutT, D, D);
    transpose_cast_k<<<dim3(F / 32, D / 32, L),     tb, 0, stream>>>(W1, W1T, D, F);
    transpose_cast_k<<<dim3(D / 32, F / 32, L),     tb, 0, stream>>>(W2, W2T, F, D);
    transpose_cast_k<<<dim3(V / 32, D / 32, 1),     tb, 0, stream>>>(Whead, WheadT, D, V);

    embed_k<<<M, 256, 0, stream>>>(tokens, token_emb, x);

    for (int lyr = 0; lyr < L; ++lyr) {
        layernorm_k<<<M, 256, 0, stream>>>(x, ln1_s + lyr * D, ln1_b + lyr * D, h);
        // qkv GEMM: Q,K cols -> qkv buffer; V cols -> vt (transposed) directly
        gemm_bt_k<5><<<dim3(M / 128, 3 * D / 128), 256, 0, stream>>>(
            h, WqkvT + (size_t)lyr * 3 * D * D, nullptr, qkv, vt, nullptr, M, 3 * D, D);
        attn_mfma_k<<<B * H * S / 64, 256, 0, stream>>>(qkv, vt, ob);
        gemm_bt_k<1, 4><<<dim3(M / 128, D / 128, 4), 256, 0, stream>>>(
            ob, WoutT + (size_t)lyr * D * D, x, nullptr, nullptr, nullptr, M, D, D);
        layernorm_k<<<M, 256, 0, stream>>>(x, ln2_s + lyr * D, ln2_b + lyr * D, h);
        gemm_bt_k<2><<<dim3(M / 128, F / 128), 256, 0, stream>>>(
            h, W1T + (size_t)lyr * F * D, nullptr, mid, nullptr, b1 + lyr * F, M, F, D);
        gemm_bt_k<3, 4><<<dim3(M / 128, D / 128, 4), 256, 0, stream>>>(
            mid, W2T + (size_t)lyr * D * F, x, nullptr, nullptr, b2 + lyr * D, M, D, F);
    }
    layernorm_k<<<M, 256, 0, stream>>>(x, lnf_s, lnf_b, h);
    gemm_bt_k<4><<<dim3(M / 128, V / 128), 256, 0, stream>>>(
        h, WheadT, out, nullptr, nullptr, bhead, M, V, D);
}